// Round 3
// baseline (114.216 us; speedup 1.0000x reference)
//
#include <hip/hip_runtime.h>

// out[i] = cos(in[i]) — the 2-qubit circuit's <Z0>,<Z1> reduce to cos(r1),cos(r2)
// (RZZ is a pure phase; probs unchanged; ENTANGLE_STRENGTH=0 anyway).
// Memory-bound streaming: 64 MB in + 64 MB out, each touched exactly once.
// Non-temporal loads/stores (nt) skip cache allocation; 2 vec4/thread for ILP.
// NOTE: __builtin_nontemporal_* requires a clang vector type, not HIP float4.

typedef float fvec4 __attribute__((ext_vector_type(4)));

__global__ __launch_bounds__(256) void qfl_cos_kernel(const fvec4* __restrict__ in,
                                                      fvec4* __restrict__ out,
                                                      int n4) {
    int i = blockIdx.x * blockDim.x + threadIdx.x;
    int stride = gridDim.x * blockDim.x;
    for (; i < n4; i += stride) {
        fvec4 v = __builtin_nontemporal_load(&in[i]);
        fvec4 r;
        r.x = __cosf(v.x);
        r.y = __cosf(v.y);
        r.z = __cosf(v.z);
        r.w = __cosf(v.w);
        __builtin_nontemporal_store(r, &out[i]);
    }
}

// Scalar tail (n not divisible by 4 — not expected here, but safe).
__global__ void qfl_cos_tail(const float* __restrict__ in,
                             float* __restrict__ out,
                             int start, int n) {
    int i = start + blockIdx.x * blockDim.x + threadIdx.x;
    if (i < n) out[i] = __cosf(in[i]);
}

extern "C" void kernel_launch(void* const* d_in, const int* in_sizes, int n_in,
                              void* d_out, int out_size, void* d_ws, size_t ws_size,
                              hipStream_t stream) {
    const float* in = (const float*)d_in[0];
    float* out = (float*)d_out;
    int n = in_sizes[0];          // 16,777,216 floats (BATCH x 2)
    int n4 = n >> 2;              // 4,194,304 vec4 groups

    if (n4 > 0) {
        const int block = 256;
        // 2 vec4 per thread: 8192 blocks cover n4=4M with stride 2M.
        int grid = (n4 + block * 2 - 1) / (block * 2);
        qfl_cos_kernel<<<grid, block, 0, stream>>>((const fvec4*)in, (fvec4*)out, n4);
    }
    int tail_start = n4 << 2;
    int tail = n - tail_start;
    if (tail > 0) {
        qfl_cos_tail<<<1, 64, 0, stream>>>(in, out, tail_start, n);
    }
}

// Round 4
// 106.959 us; speedup vs baseline: 1.0678x; 1.0678x over previous
//
#include <hip/hip_runtime.h>

// out[i] = cos(in[i]) — the 2-qubit circuit's <Z0>,<Z1> reduce to cos(r1),cos(r2)
// (RZZ is a pure phase; probs unchanged; ENTANGLE_STRENGTH=0 anyway).
// Memory-bound: 64 MB in + 64 MB out, each touched exactly once.
// R3 post-mortem: nontemporal load/store + grid-stride REGRESSED (108→114 µs);
// this is the measured-best R0 form: one float4/thread, exact cover, plain
// cached loads/stores (dwordx4).

__global__ __launch_bounds__(256) void qfl_cos_kernel(const float4* __restrict__ in,
                                                      float4* __restrict__ out,
                                                      int n4) {
    int i = blockIdx.x * blockDim.x + threadIdx.x;
    if (i < n4) {
        float4 v = in[i];
        float4 r;
        r.x = __cosf(v.x);
        r.y = __cosf(v.y);
        r.z = __cosf(v.z);
        r.w = __cosf(v.w);
        out[i] = r;
    }
}

// Scalar tail (n not divisible by 4 — not expected here, but safe).
__global__ void qfl_cos_tail(const float* __restrict__ in,
                             float* __restrict__ out,
                             int start, int n) {
    int i = start + blockIdx.x * blockDim.x + threadIdx.x;
    if (i < n) out[i] = __cosf(in[i]);
}

extern "C" void kernel_launch(void* const* d_in, const int* in_sizes, int n_in,
                              void* d_out, int out_size, void* d_ws, size_t ws_size,
                              hipStream_t stream) {
    const float* in = (const float*)d_in[0];
    float* out = (float*)d_out;
    int n = in_sizes[0];          // 16,777,216 floats (BATCH x 2)
    int n4 = n >> 2;              // 4,194,304 float4 groups

    if (n4 > 0) {
        int block = 256;
        int grid = (n4 + block - 1) / block;
        qfl_cos_kernel<<<grid, block, 0, stream>>>((const float4*)in, (float4*)out, n4);
    }
    int tail_start = n4 << 2;
    int tail = n - tail_start;
    if (tail > 0) {
        qfl_cos_tail<<<1, 64, 0, stream>>>(in, out, tail_start, n);
    }
}